// Round 1
// baseline (184.574 us; speedup 1.0000x reference)
//
#include <hip/hip_runtime.h>
#include <hip/hip_bf16.h>

#define NUM_SLOTS 168
#define NUM_CATS 2048
#define BATCH 512
#define SEQ 200

// Kernel 1: row-wise softmax of the [168, 2048] matrix into workspace.
// One block (256 threads) per row; each thread owns 8 elements.
__global__ void softmax_rows_kernel(const float* __restrict__ mat,
                                    float* __restrict__ probs) {
    const int row = blockIdx.x;
    const float* r = mat + row * NUM_CATS;
    float* o = probs + row * NUM_CATS;
    const int t = threadIdx.x;

    float vals[8];
    float mx = -INFINITY;
#pragma unroll
    for (int j = 0; j < 8; ++j) {
        vals[j] = r[t + j * 256];
        mx = fmaxf(mx, vals[j]);
    }
    // wave (64-lane) butterfly max
#pragma unroll
    for (int off = 32; off >= 1; off >>= 1) mx = fmaxf(mx, __shfl_xor(mx, off));

    __shared__ float redmax[4];
    __shared__ float redsum[4];
    const int wave = t >> 6;
    if ((t & 63) == 0) redmax[wave] = mx;
    __syncthreads();
    mx = fmaxf(fmaxf(redmax[0], redmax[1]), fmaxf(redmax[2], redmax[3]));

    float sum = 0.0f;
#pragma unroll
    for (int j = 0; j < 8; ++j) {
        vals[j] = expf(vals[j] - mx);
        sum += vals[j];
    }
#pragma unroll
    for (int off = 32; off >= 1; off >>= 1) sum += __shfl_xor(sum, off);
    if ((t & 63) == 0) redsum[wave] = sum;
    __syncthreads();
    sum = redsum[0] + redsum[1] + redsum[2] + redsum[3];

    const float inv = 1.0f / sum;
#pragma unroll
    for (int j = 0; j < 8; ++j) o[t + j * 256] = vals[j] * inv;
}

// Kernel 2: gather expanded output. Each float4 index i maps to
// output row i>>9 (512 float4 per 2048-cat row) and within-row slot i&511.
// probs table (1.37 MB) stays L2-resident; writes are the streaming cost.
__global__ void gather_rows_kernel(const int* __restrict__ hours,
                                   const float4* __restrict__ probs,
                                   float4* __restrict__ out,
                                   int total4) {
    const int stride = gridDim.x * blockDim.x;
    for (int i = blockIdx.x * blockDim.x + threadIdx.x; i < total4; i += stride) {
        const int row = i >> 9;        // which (batch,seq) element
        const int v = i & 511;         // float4 slot within the 2048-cat row
        const int h = hours[row];      // 0..167, tiny array, cache-resident
        out[i] = probs[(h << 9) + v];
    }
}

extern "C" void kernel_launch(void* const* d_in, const int* in_sizes, int n_in,
                              void* d_out, int out_size, void* d_ws, size_t ws_size,
                              hipStream_t stream) {
    const int* inputs_hour = (const int*)d_in[0];            // [512, 200] int32
    const float* catid_time_matrix = (const float*)d_in[1];  // [168, 2048] f32
    float* out = (float*)d_out;                               // [512, 200, 2048] f32
    float* probs = (float*)d_ws;                              // 168*2048 f32 = 1.38 MB

    // Step 1: softmax (tiny)
    softmax_rows_kernel<<<NUM_SLOTS, 256, 0, stream>>>(catid_time_matrix, probs);

    // Step 2: gather/expand (write-BW-bound)
    const int total4 = (BATCH * SEQ * NUM_CATS) / 4;  // 52,428,800 float4
    const int blocks = 2048;                           // 8 blocks/CU, grid-stride
    gather_rows_kernel<<<blocks, 256, 0, stream>>>(
        inputs_hour, (const float4*)probs, (float4*)out, total4);
}

// Round 3
// 180.635 us; speedup vs baseline: 1.0218x; 1.0218x over previous
//
#include <hip/hip_runtime.h>
#include <hip/hip_bf16.h>

#define NUM_SLOTS 168
#define NUM_CATS 2048
#define BATCH 512
#define SEQ 200

// Native clang vector type — __builtin_nontemporal_store requires a vector of
// scalars, not HIP's HIP_vector_type class.
typedef float v4f __attribute__((ext_vector_type(4)));

// Kernel 1: row-wise softmax of the [168, 2048] matrix into workspace.
// One block (256 threads) per row; each thread owns 8 elements.
__global__ void softmax_rows_kernel(const float* __restrict__ mat,
                                    float* __restrict__ probs) {
    const int row = blockIdx.x;
    const float* r = mat + row * NUM_CATS;
    float* o = probs + row * NUM_CATS;
    const int t = threadIdx.x;

    float vals[8];
    float mx = -INFINITY;
#pragma unroll
    for (int j = 0; j < 8; ++j) {
        vals[j] = r[t + j * 256];
        mx = fmaxf(mx, vals[j]);
    }
    // wave (64-lane) butterfly max
#pragma unroll
    for (int off = 32; off >= 1; off >>= 1) mx = fmaxf(mx, __shfl_xor(mx, off));

    __shared__ float redmax[4];
    __shared__ float redsum[4];
    const int wave = t >> 6;
    if ((t & 63) == 0) redmax[wave] = mx;
    __syncthreads();
    mx = fmaxf(fmaxf(redmax[0], redmax[1]), fmaxf(redmax[2], redmax[3]));

    float sum = 0.0f;
#pragma unroll
    for (int j = 0; j < 8; ++j) {
        vals[j] = expf(vals[j] - mx);
        sum += vals[j];
    }
#pragma unroll
    for (int off = 32; off >= 1; off >>= 1) sum += __shfl_xor(sum, off);
    if ((t & 63) == 0) redsum[wave] = sum;
    __syncthreads();
    sum = redsum[0] + redsum[1] + redsum[2] + redsum[3];

    const float inv = 1.0f / sum;
#pragma unroll
    for (int j = 0; j < 8; ++j) o[t + j * 256] = vals[j] * inv;
}

// Kernel 2: gather/expand. Non-temporal 16B stores (don't allocate the
// 839 MB output stream in the 4 MiB per-XCD L2 — keep the 1.37 MB probs
// table resident there). Unroll x2 for two independent load->store pairs
// in flight per wave.
__global__ void gather_rows_kernel(const int* __restrict__ hours,
                                   const v4f* __restrict__ probs,
                                   v4f* __restrict__ out,
                                   int total4) {
    const int gsz = gridDim.x * blockDim.x;
    int i = blockIdx.x * blockDim.x + threadIdx.x;
    const int step = gsz * 2;

    for (; i + gsz < total4; i += step) {
        const int i0 = i;
        const int i1 = i + gsz;
        const int h0 = hours[i0 >> 9];
        const int h1 = hours[i1 >> 9];
        const v4f v0 = probs[(h0 << 9) + (i0 & 511)];
        const v4f v1 = probs[(h1 << 9) + (i1 & 511)];
        __builtin_nontemporal_store(v0, &out[i0]);
        __builtin_nontemporal_store(v1, &out[i1]);
    }
    for (; i < total4; i += gsz) {
        const int h = hours[i >> 9];
        __builtin_nontemporal_store(probs[(h << 9) + (i & 511)], &out[i]);
    }
}

extern "C" void kernel_launch(void* const* d_in, const int* in_sizes, int n_in,
                              void* d_out, int out_size, void* d_ws, size_t ws_size,
                              hipStream_t stream) {
    const int* inputs_hour = (const int*)d_in[0];            // [512, 200] int32
    const float* catid_time_matrix = (const float*)d_in[1];  // [168, 2048] f32
    float* out = (float*)d_out;                               // [512, 200, 2048] f32
    float* probs = (float*)d_ws;                              // 168*2048 f32 = 1.38 MB

    // Step 1: softmax (tiny)
    softmax_rows_kernel<<<NUM_SLOTS, 256, 0, stream>>>(catid_time_matrix, probs);

    // Step 2: gather/expand (write-BW-bound)
    const int total4 = (BATCH * SEQ * NUM_CATS) / 4;  // 52,428,800 float4
    const int blocks = 2048;                           // 8 blocks/CU, grid-stride
    gather_rows_kernel<<<blocks, 256, 0, stream>>>(
        inputs_hour, (const v4f*)probs, (v4f*)out, total4);
}

// Round 4
// 175.154 us; speedup vs baseline: 1.0538x; 1.0313x over previous
//
#include <hip/hip_runtime.h>
#include <hip/hip_bf16.h>

#define NUM_SLOTS 168
#define NUM_CATS 2048
#define BATCH 512
#define SEQ 200
#define ROWS_PER_BLOCK 50   // 2048 blocks * 50 = 102,400 = BATCH*SEQ exactly

// Native clang vector type — __builtin_nontemporal_store requires a vector of
// scalars, not HIP's HIP_vector_type class.
typedef float v4f __attribute__((ext_vector_type(4)));

// Kernel 1: row-wise softmax of the [168, 2048] matrix into workspace.
// One block (256 threads) per row; each thread owns 8 elements.
__global__ void softmax_rows_kernel(const float* __restrict__ mat,
                                    float* __restrict__ probs) {
    const int row = blockIdx.x;
    const float* r = mat + row * NUM_CATS;
    float* o = probs + row * NUM_CATS;
    const int t = threadIdx.x;

    float vals[8];
    float mx = -INFINITY;
#pragma unroll
    for (int j = 0; j < 8; ++j) {
        vals[j] = r[t + j * 256];
        mx = fmaxf(mx, vals[j]);
    }
    // wave (64-lane) butterfly max
#pragma unroll
    for (int off = 32; off >= 1; off >>= 1) mx = fmaxf(mx, __shfl_xor(mx, off));

    __shared__ float redmax[4];
    __shared__ float redsum[4];
    const int wave = t >> 6;
    if ((t & 63) == 0) redmax[wave] = mx;
    __syncthreads();
    mx = fmaxf(fmaxf(redmax[0], redmax[1]), fmaxf(redmax[2], redmax[3]));

    float sum = 0.0f;
#pragma unroll
    for (int j = 0; j < 8; ++j) {
        vals[j] = expf(vals[j] - mx);
        sum += vals[j];
    }
#pragma unroll
    for (int off = 32; off >= 1; off >>= 1) sum += __shfl_xor(sum, off);
    if ((t & 63) == 0) redsum[wave] = sum;
    __syncthreads();
    sum = redsum[0] + redsum[1] + redsum[2] + redsum[3];

    const float inv = 1.0f / sum;
#pragma unroll
    for (int j = 0; j < 8; ++j) o[t + j * 256] = vals[j] * inv;
}

// Kernel 2: gather/expand, row-block mapping. Each block owns ROWS_PER_BLOCK
// complete output rows, so hours[row] is block-uniform -> scalar load (s_load)
// off the vector-memory critical path, and the probs row base lives in SGPRs.
// Per row each thread does 2 coalesced 16B loads + 2 nt 16B stores at
// uniform-base + lane-stride. Unroll x2 gives 4 independent loads in flight.
__global__ void __launch_bounds__(256)
gather_rows_kernel(const int* __restrict__ hours,
                   const v4f* __restrict__ probs,
                   v4f* __restrict__ out) {
    const int t = threadIdx.x;                       // 0..255
    const int row0 = blockIdx.x * ROWS_PER_BLOCK;
#pragma unroll 2
    for (int r = 0; r < ROWS_PER_BLOCK; ++r) {
        const int row = row0 + r;
        const int h = hours[row];                    // uniform -> scalar cache
        const v4f* __restrict__ src = probs + (h << 9);
        v4f* __restrict__ dst = out + ((size_t)row << 9);
        const v4f a = src[t];
        const v4f b = src[t + 256];
        __builtin_nontemporal_store(a, &dst[t]);
        __builtin_nontemporal_store(b, &dst[t + 256]);
    }
}

extern "C" void kernel_launch(void* const* d_in, const int* in_sizes, int n_in,
                              void* d_out, int out_size, void* d_ws, size_t ws_size,
                              hipStream_t stream) {
    const int* inputs_hour = (const int*)d_in[0];            // [512, 200] int32
    const float* catid_time_matrix = (const float*)d_in[1];  // [168, 2048] f32
    float* out = (float*)d_out;                               // [512, 200, 2048] f32
    float* probs = (float*)d_ws;                              // 168*2048 f32 = 1.38 MB

    // Step 1: softmax (tiny)
    softmax_rows_kernel<<<NUM_SLOTS, 256, 0, stream>>>(catid_time_matrix, probs);

    // Step 2: gather/expand (write-BW-bound), 2048 blocks = 8/CU, all resident
    gather_rows_kernel<<<(BATCH * SEQ) / ROWS_PER_BLOCK, 256, 0, stream>>>(
        inputs_hour, (const v4f*)probs, (v4f*)out);
}